// Round 4
// baseline (1944.501 us; speedup 1.0000x reference)
//
#include <hip/hip_runtime.h>
#include <hip/hip_bf16.h>
#include <stdint.h>

#define NF 165
#define NH 128
#define NCOLS 384
#define KT 15
#define NKT 11

// ---- CSR build ----------------------------------------------------------

__global__ __launch_bounds__(256) void k_count(
        const int* __restrict__ erow, int* __restrict__ cnt, int E) {
    int e = blockIdx.x * 256 + threadIdx.x;
    if (e >= E) return;
    atomicAdd(&cnt[erow[e]], 1);
}

__global__ __launch_bounds__(256) void k_dis(
        const int* __restrict__ cnt, float* __restrict__ dis, int N) {
    int i = blockIdx.x * 256 + threadIdx.x;
    if (i >= N) return;
    int d = cnt[i];
    dis[i] = (d > 0) ? rsqrtf((float)d) : 0.0f;
}

__global__ __launch_bounds__(256) void k_scan1(
        const int* __restrict__ cnt, int* __restrict__ off,
        int* __restrict__ bsum, int N) {
    __shared__ int sh[256];
    int t = threadIdx.x;
    int base = blockIdx.x * 1024 + t * 4;
    int v0 = (base + 0 < N) ? cnt[base + 0] : 0;
    int v1 = (base + 1 < N) ? cnt[base + 1] : 0;
    int v2 = (base + 2 < N) ? cnt[base + 2] : 0;
    int v3 = (base + 3 < N) ? cnt[base + 3] : 0;
    int tsum = v0 + v1 + v2 + v3;
    sh[t] = tsum;
    __syncthreads();
#pragma unroll
    for (int ofs = 1; ofs < 256; ofs <<= 1) {
        int x = (t >= ofs) ? sh[t - ofs] : 0;
        __syncthreads();
        sh[t] += x;
        __syncthreads();
    }
    int excl = sh[t] - tsum;
    if (t == 255) bsum[blockIdx.x] = sh[t];
    if (base + 0 < N) off[base + 0] = excl;
    excl += v0;
    if (base + 1 < N) off[base + 1] = excl;
    excl += v1;
    if (base + 2 < N) off[base + 2] = excl;
    excl += v2;
    if (base + 3 < N) off[base + 3] = excl;
}

__global__ __launch_bounds__(256) void k_scan2(int* __restrict__ bsum, int NB) {
    __shared__ int sh[256];
    int t = threadIdx.x;
    int v = (t < NB) ? bsum[t] : 0;
    sh[t] = v;
    __syncthreads();
#pragma unroll
    for (int ofs = 1; ofs < 256; ofs <<= 1) {
        int x = (t >= ofs) ? sh[t - ofs] : 0;
        __syncthreads();
        sh[t] += x;
        __syncthreads();
    }
    if (t < NB) bsum[t] = sh[t] - v;
}

__global__ __launch_bounds__(256) void k_scan3(
        int* __restrict__ off, int* __restrict__ cur,
        const int* __restrict__ bsum, int N, int E) {
    int i = blockIdx.x * 256 + threadIdx.x;
    if (i >= N) return;
    int v = off[i] + bsum[i >> 10];
    off[i] = v;
    cur[i] = v;
    if (i == 0) off[N] = E;
}

__global__ __launch_bounds__(256) void k_scatter(
        const int* __restrict__ erow, const int* __restrict__ ecol,
        const float* __restrict__ dis, int* __restrict__ cur,
        int* __restrict__ scol, float* __restrict__ snrm, int E) {
    int e = blockIdx.x * 256 + threadIdx.x;
    if (e >= E) return;
    int r = erow[e];
    int c = ecol[e];
    int pos = atomicAdd(&cur[r], 1);
    scol[pos] = c;
    snrm[pos] = -dis[r] * dis[c];
}

// ---- weights ------------------------------------------------------------

__global__ __launch_bounds__(256) void k_wc1(const float* __restrict__ W1,
                                             float* __restrict__ Wc1) {
    int gid = blockIdx.x * 256 + threadIdx.x;
    if (gid >= NF * NCOLS) return;
    int i = gid / NCOLS;
    int j = gid % NCOLS;
    float v;
    if (j < 128)      v = W1[i * 128 + j] - W1[2 * 21120 + i * 128 + j];
    else if (j < 256) v = W1[21120 + i * 128 + (j - 128)];
    else              v = W1[42240 + i * 128 + (j - 256)];
    Wc1[gid] = v;
}

__global__ __launch_bounds__(256) void k_wc2(const float* __restrict__ W2,
                                             float* __restrict__ Wc2) {
    int gid = blockIdx.x * 256 + threadIdx.x;
    if (gid >= 128 * 8) return;
    int k = gid >> 3;
    int c = gid & 7;
    float v = 0.0f;
    if (c < 2)      v = W2[k * 2 + c] - W2[512 + k * 2 + c];
    else if (c < 4) v = W2[256 + k * 2 + (c - 2)];
    else if (c < 6) v = W2[512 + k * 2 + (c - 4)];
    Wc2[gid] = v;
}

// ---- dense kernels ------------------------------------------------------

// GEMM1: x[N,165] @ Wc1[165,384] -> u | s | w
// One column pass: tile 64 rows x 384 cols, 256 threads, 8x12 per thread.
// Per k-step: 5 ds_read_b128 (80 B) feed 96 FMAs -> VALU-bound (0.83 B/FLOP).
__global__ __launch_bounds__(256) void k_gemm1(
        const float* __restrict__ x, const float* __restrict__ Wc,
        float* __restrict__ u, float* __restrict__ s, float* __restrict__ w, int N) {
    __shared__ float As[KT][64];
    __shared__ float Bs[KT][NCOLS];

    int row0 = blockIdx.x * 64;
    int tid = threadIdx.x;
    int tx = tid & 31;    // col group: cols tx*12 .. tx*12+11
    int ty = tid >> 5;    // row group: rows ty*8 .. ty*8+7

    float acc[8][12] = {};

    for (int kt = 0; kt < NKT; ++kt) {
        int k0 = kt * KT;
        for (int idx = tid; idx < 64 * KT; idx += 256) {
            int r = idx & 63;
            int k = idx >> 6;
            int row = row0 + r;
            As[k][r] = (row < N) ? x[(size_t)row * NF + k0 + k] : 0.0f;
        }
        for (int idx = tid; idx < KT * NCOLS / 4; idx += 256) {
            int k = idx / 96;
            int c4 = (idx - k * 96) * 4;
            *(float4*)&Bs[k][c4] = *(const float4*)&Wc[(size_t)(k0 + k) * NCOLS + c4];
        }
        __syncthreads();
#pragma unroll
        for (int kk = 0; kk < KT; ++kk) {
            float4 a0 = *(const float4*)&As[kk][ty * 8];
            float4 a1 = *(const float4*)&As[kk][ty * 8 + 4];
            float4 b0 = *(const float4*)&Bs[kk][tx * 12];
            float4 b1 = *(const float4*)&Bs[kk][tx * 12 + 4];
            float4 b2 = *(const float4*)&Bs[kk][tx * 12 + 8];
            float av[8] = {a0.x, a0.y, a0.z, a0.w, a1.x, a1.y, a1.z, a1.w};
            float bv[12] = {b0.x, b0.y, b0.z, b0.w, b1.x, b1.y, b1.z, b1.w,
                            b2.x, b2.y, b2.z, b2.w};
#pragma unroll
            for (int i = 0; i < 8; ++i)
#pragma unroll
                for (int j = 0; j < 12; ++j)
                    acc[i][j] += av[i] * bv[j];
        }
        __syncthreads();
    }

#pragma unroll
    for (int i = 0; i < 8; ++i) {
        int row = row0 + ty * 8 + i;
        if (row < N) {
#pragma unroll
            for (int j3 = 0; j3 < 3; ++j3) {
                int c4 = tx * 12 + j3 * 4;
                int g = c4 >> 7;
                int cc = c4 & 127;
                float* dst = (g == 0) ? u : (g == 1) ? s : w;
                float4 v = {acc[i][j3 * 4 + 0], acc[i][j3 * 4 + 1],
                            acc[i][j3 * 4 + 2], acc[i][j3 * 4 + 3]};
                *(float4*)(dst + (size_t)row * NH + cc) = v;
            }
        }
    }
}

// CSR prop, 128-wide: dst[r] = add[r] + scale * sum_e nrm[e]*src[col[e]]
// One wave per row, unroll-2 for two gathers in flight.
__global__ __launch_bounds__(256) void k_prop128_csr(
        const int* __restrict__ off, const int* __restrict__ scol,
        const float* __restrict__ snrm, const float* __restrict__ src,
        const float* __restrict__ add, float* __restrict__ dst,
        float scale, int N) {
    int wid = (blockIdx.x * 256 + threadIdx.x) >> 6;
    if (wid >= N) return;
    int lane = threadIdx.x & 63;
    int e0 = off[wid], e1 = off[wid + 1];
    float a0 = 0.0f, a1 = 0.0f, b0 = 0.0f, b1 = 0.0f;
    int e = e0;
    for (; e + 2 <= e1; e += 2) {
        int c0 = scol[e];
        int c1 = scol[e + 1];
        float n0 = snrm[e];
        float n1 = snrm[e + 1];
        float2 v0 = *(const float2*)(src + (size_t)c0 * NH + lane * 2);
        float2 v1 = *(const float2*)(src + (size_t)c1 * NH + lane * 2);
        a0 += n0 * v0.x; a1 += n0 * v0.y;
        b0 += n1 * v1.x; b1 += n1 * v1.y;
    }
    if (e < e1) {
        int c0 = scol[e];
        float n0 = snrm[e];
        float2 v0 = *(const float2*)(src + (size_t)c0 * NH + lane * 2);
        a0 += n0 * v0.x; a1 += n0 * v0.y;
    }
    a0 += b0; a1 += b1;
    float2 ad = *(const float2*)(add + (size_t)wid * NH + lane * 2);
    float2 o = {ad.x + scale * a0, ad.y + scale * a1};
    *(float2*)(dst + (size_t)wid * NH + lane * 2) = o;
}

// h = relu(u + b1) (float4)
__global__ __launch_bounds__(256) void k_relu_bias(
        const float* __restrict__ u, const float* __restrict__ b1,
        float* __restrict__ h, int n4) {
    int i = blockIdx.x * 256 + threadIdx.x;
    if (i >= n4) return;
    float4 v = ((const float4*)u)[i];
    float4 bb = ((const float4*)b1)[i & 31];
    v.x = fmaxf(v.x + bb.x, 0.0f);
    v.y = fmaxf(v.y + bb.y, 0.0f);
    v.z = fmaxf(v.z + bb.z, 0.0f);
    v.w = fmaxf(v.w + bb.w, 0.0f);
    ((float4*)h)[i] = v;
}

// GEMM2: h[N,128] @ Wc2[128,8] -> out(+b2), s2, w2
__global__ __launch_bounds__(256) void k_gemm2(
        const float* __restrict__ h, const float* __restrict__ Wc2,
        const float* __restrict__ b2, float* __restrict__ out,
        float* __restrict__ s2, float* __restrict__ w2, int N) {
    __shared__ float Ws[128 * 8];
    int tid = threadIdx.x;
    for (int idx = tid; idx < 128 * 8; idx += 256) Ws[idx] = Wc2[idx];
    __syncthreads();

    int rl = tid >> 3;
    int sub = tid & 7;
    int row = blockIdx.x * 32 + rl;
    if (row >= N) return;

    float4 accA = {0, 0, 0, 0};
    float4 accB = {0, 0, 0, 0};
    const float4* hp = (const float4*)(h + (size_t)row * NH + sub * 16);
#pragma unroll
    for (int q = 0; q < 4; ++q) {
        float4 hv = hp[q];
        float he[4] = {hv.x, hv.y, hv.z, hv.w};
#pragma unroll
        for (int t = 0; t < 4; ++t) {
            int k = sub * 16 + q * 4 + t;
            float4 wa = *(const float4*)&Ws[k * 8 + 0];
            float4 wb = *(const float4*)&Ws[k * 8 + 4];
            accA.x += he[t] * wa.x; accA.y += he[t] * wa.y;
            accA.z += he[t] * wa.z; accA.w += he[t] * wa.w;
            accB.x += he[t] * wb.x; accB.y += he[t] * wb.y;
        }
    }
#pragma unroll
    for (int off = 4; off; off >>= 1) {
        accA.x += __shfl_xor(accA.x, off);
        accA.y += __shfl_xor(accA.y, off);
        accA.z += __shfl_xor(accA.z, off);
        accA.w += __shfl_xor(accA.w, off);
        accB.x += __shfl_xor(accB.x, off);
        accB.y += __shfl_xor(accB.y, off);
    }
    if (sub == 0) {
        out[(size_t)row * 2 + 0] = accA.x + b2[0];
        out[(size_t)row * 2 + 1] = accA.y + b2[1];
        s2[(size_t)row * 2 + 0] = accA.z;
        s2[(size_t)row * 2 + 1] = accA.w;
        w2[(size_t)row * 2 + 0] = accB.x;
        w2[(size_t)row * 2 + 1] = accB.y;
    }
}

// CSR prop, 2-wide: one thread per row.
__global__ __launch_bounds__(256) void k_prop2_csr(
        const int* __restrict__ off, const int* __restrict__ scol,
        const float* __restrict__ snrm, const float* __restrict__ src,
        const float* __restrict__ add, float* __restrict__ dst,
        float scale, int N) {
    int r = blockIdx.x * 256 + threadIdx.x;
    if (r >= N) return;
    int e0 = off[r], e1 = off[r + 1];
    float a0 = 0.0f, a1 = 0.0f;
    for (int e = e0; e < e1; ++e) {
        int c = scol[e];
        float nv = snrm[e];
        float2 v = *(const float2*)(src + (size_t)c * 2);
        a0 += nv * v.x;
        a1 += nv * v.y;
    }
    float2 ad = *(const float2*)(add + (size_t)r * 2);
    float2 o = {ad.x + scale * a0, ad.y + scale * a1};
    *(float2*)(dst + (size_t)r * 2) = o;
}

extern "C" void kernel_launch(void* const* d_in, const int* in_sizes, int n_in,
                              void* d_out, int out_size, void* d_ws, size_t ws_size,
                              hipStream_t stream) {
    const float* x   = (const float*)d_in[0];
    const int* eidx  = (const int*)d_in[1];   // harness converts int64 -> int32
    const float* W1  = (const float*)d_in[2];
    const float* b1  = (const float*)d_in[3];
    const float* W2  = (const float*)d_in[4];
    const float* b2  = (const float*)d_in[5];
    float* out       = (float*)d_out;

    int N = in_sizes[0] / NF;
    int E = in_sizes[1] / 2;
    const int* erow = eidx;
    const int* ecol = eidx + E;

    char* p = (char*)d_ws;
    auto alloc = [&](size_t bytes) {
        char* q = p;
        p += (bytes + 255) & ~(size_t)255;
        return q;
    };
    float* u    = (float*)alloc((size_t)N * NH * 4);
    float* s    = (float*)alloc((size_t)N * NH * 4);
    float* w    = (float*)alloc((size_t)N * NH * 4);   // later reused as h
    float* dis  = (float*)alloc((size_t)N * 4);
    int* cnt    = (int*)alloc((size_t)N * 4);
    int* off    = (int*)alloc((size_t)(N + 1) * 4);
    int* cur    = (int*)alloc((size_t)N * 4);
    int* bsum   = (int*)alloc((size_t)256 * 4);
    int* scol   = (int*)alloc((size_t)E * 4);
    float* snrm = (float*)alloc((size_t)E * 4);
    float* Wc1  = (float*)alloc((size_t)NF * NCOLS * 4);
    float* Wc2  = (float*)alloc((size_t)128 * 8 * 4);
    float* s2   = (float*)alloc((size_t)N * 2 * 4);
    float* w2   = (float*)alloc((size_t)N * 2 * 4);

    hipMemsetAsync(cnt, 0, (size_t)N * 4, stream);

    int gE = (E + 255) / 256;
    int gN = (N + 255) / 256;
    int NB = (N + 1023) / 1024;

    // CSR build
    k_count<<<gE, 256, 0, stream>>>(erow, cnt, E);
    k_dis<<<gN, 256, 0, stream>>>(cnt, dis, N);
    k_scan1<<<NB, 256, 0, stream>>>(cnt, off, bsum, N);
    k_scan2<<<1, 256, 0, stream>>>(bsum, NB);
    k_scan3<<<gN, 256, 0, stream>>>(off, cur, bsum, N, E);
    k_scatter<<<gE, 256, 0, stream>>>(erow, ecol, dis, cur, scol, snrm, E);

    // weights
    k_wc1<<<(NF * NCOLS + 255) / 256, 256, 0, stream>>>(W1, Wc1);
    k_wc2<<<4, 256, 0, stream>>>(W2, Wc2);

    // layer 1
    int g1 = (N + 63) / 64;
    k_gemm1<<<g1, 256, 0, stream>>>(x, Wc1, u, s, w, N);

    int gW = (N * 64 + 255) / 256;   // one wave per row
    // s = s + 2*prop(w)
    k_prop128_csr<<<gW, 256, 0, stream>>>(off, scol, snrm, w, s, s, 2.0f, N);
    // u = u + prop(s)
    k_prop128_csr<<<gW, 256, 0, stream>>>(off, scol, snrm, s, u, u, 1.0f, N);

    int n4 = N * NH / 4;
    k_relu_bias<<<(n4 + 255) / 256, 256, 0, stream>>>(u, b1, w, n4);

    // layer 2
    k_gemm2<<<(N + 31) / 32, 256, 0, stream>>>(w, Wc2, b2, out, s2, w2, N);
    // s2 = s2 + 2*prop(w2)
    k_prop2_csr<<<gN, 256, 0, stream>>>(off, scol, snrm, w2, s2, s2, 2.0f, N);
    // out = out + prop(s2)
    k_prop2_csr<<<gN, 256, 0, stream>>>(off, scol, snrm, s2, out, out, 1.0f, N);
}

// Round 5
// 1593.175 us; speedup vs baseline: 1.2205x; 1.2205x over previous
//
#include <hip/hip_runtime.h>
#include <hip/hip_bf16.h>
#include <stdint.h>

#define NF 165
#define NH 128
#define NCOLS 384
#define KT 15
#define NKT 11

// ---- bf16 helpers (raw ushort to keep codegen simple) --------------------

__device__ __forceinline__ unsigned short f2bf(float f) {
    unsigned int u = __builtin_bit_cast(unsigned int, f);
    u = (u + 0x7FFFu + ((u >> 16) & 1u)) >> 16;   // RNE
    return (unsigned short)u;
}
__device__ __forceinline__ float bf2f_lo(unsigned int v) {
    return __builtin_bit_cast(float, v << 16);
}
__device__ __forceinline__ float bf2f_hi(unsigned int v) {
    return __builtin_bit_cast(float, v & 0xFFFF0000u);
}

// ---- CSR build ----------------------------------------------------------

__global__ __launch_bounds__(256) void k_count(
        const int* __restrict__ erow, int* __restrict__ cnt, int E) {
    int e = blockIdx.x * 256 + threadIdx.x;
    if (e >= E) return;
    atomicAdd(&cnt[erow[e]], 1);
}

__global__ __launch_bounds__(256) void k_dis(
        const int* __restrict__ cnt, float* __restrict__ dis, int N) {
    int i = blockIdx.x * 256 + threadIdx.x;
    if (i >= N) return;
    int d = cnt[i];
    dis[i] = (d > 0) ? rsqrtf((float)d) : 0.0f;
}

__global__ __launch_bounds__(256) void k_scan1(
        const int* __restrict__ cnt, int* __restrict__ off,
        int* __restrict__ bsum, int N) {
    __shared__ int sh[256];
    int t = threadIdx.x;
    int base = blockIdx.x * 1024 + t * 4;
    int v0 = (base + 0 < N) ? cnt[base + 0] : 0;
    int v1 = (base + 1 < N) ? cnt[base + 1] : 0;
    int v2 = (base + 2 < N) ? cnt[base + 2] : 0;
    int v3 = (base + 3 < N) ? cnt[base + 3] : 0;
    int tsum = v0 + v1 + v2 + v3;
    sh[t] = tsum;
    __syncthreads();
#pragma unroll
    for (int ofs = 1; ofs < 256; ofs <<= 1) {
        int x = (t >= ofs) ? sh[t - ofs] : 0;
        __syncthreads();
        sh[t] += x;
        __syncthreads();
    }
    int excl = sh[t] - tsum;
    if (t == 255) bsum[blockIdx.x] = sh[t];
    if (base + 0 < N) off[base + 0] = excl;
    excl += v0;
    if (base + 1 < N) off[base + 1] = excl;
    excl += v1;
    if (base + 2 < N) off[base + 2] = excl;
    excl += v2;
    if (base + 3 < N) off[base + 3] = excl;
}

__global__ __launch_bounds__(256) void k_scan2(int* __restrict__ bsum, int NB) {
    __shared__ int sh[256];
    int t = threadIdx.x;
    int v = (t < NB) ? bsum[t] : 0;
    sh[t] = v;
    __syncthreads();
#pragma unroll
    for (int ofs = 1; ofs < 256; ofs <<= 1) {
        int x = (t >= ofs) ? sh[t - ofs] : 0;
        __syncthreads();
        sh[t] += x;
        __syncthreads();
    }
    if (t < NB) bsum[t] = sh[t] - v;
}

__global__ __launch_bounds__(256) void k_scan3(
        int* __restrict__ off, int* __restrict__ cur,
        const int* __restrict__ bsum, int N, int E) {
    int i = blockIdx.x * 256 + threadIdx.x;
    if (i >= N) return;
    int v = off[i] + bsum[i >> 10];
    off[i] = v;
    cur[i] = v;
    if (i == 0) off[N] = E;
}

__global__ __launch_bounds__(256) void k_scatter(
        const int* __restrict__ erow, const int* __restrict__ ecol,
        const float* __restrict__ dis, int* __restrict__ cur,
        int* __restrict__ scol, float* __restrict__ snrm, int E) {
    int e = blockIdx.x * 256 + threadIdx.x;
    if (e >= E) return;
    int r = erow[e];
    int c = ecol[e];
    int pos = atomicAdd(&cur[r], 1);
    scol[pos] = c;
    snrm[pos] = -dis[r] * dis[c];
}

// ---- weights ------------------------------------------------------------

__global__ __launch_bounds__(256) void k_wc1(const float* __restrict__ W1,
                                             float* __restrict__ Wc1) {
    int gid = blockIdx.x * 256 + threadIdx.x;
    if (gid >= NF * NCOLS) return;
    int i = gid / NCOLS;
    int j = gid % NCOLS;
    float v;
    if (j < 128)      v = W1[i * 128 + j] - W1[2 * 21120 + i * 128 + j];
    else if (j < 256) v = W1[21120 + i * 128 + (j - 128)];
    else              v = W1[42240 + i * 128 + (j - 256)];
    Wc1[gid] = v;
}

__global__ __launch_bounds__(256) void k_wc2(const float* __restrict__ W2,
                                             float* __restrict__ Wc2) {
    int gid = blockIdx.x * 256 + threadIdx.x;
    if (gid >= 128 * 8) return;
    int k = gid >> 3;
    int c = gid & 7;
    float v = 0.0f;
    if (c < 2)      v = W2[k * 2 + c] - W2[512 + k * 2 + c];
    else if (c < 4) v = W2[256 + k * 2 + (c - 2)];
    else if (c < 6) v = W2[512 + k * 2 + (c - 4)];
    Wc2[gid] = v;
}

// ---- GEMM1: x[N,165] @ Wc1[165,384] -> u (g0, f32) | s (g1, f32) | wb (g2, bf16)
// 128x128 tile, 256 threads, 8x8/thread as 2x2 of 4x4 sub-blocks.
__global__ __launch_bounds__(256) void k_gemm1(
        const float* __restrict__ x, const float* __restrict__ Wc,
        float* __restrict__ u, float* __restrict__ s,
        unsigned int* __restrict__ wb, int N) {
    __shared__ float As[KT][128];
    __shared__ float Bs[KT][128];

    int row0 = blockIdx.x * 128;
    int g = blockIdx.y;                 // col group 0..2
    int colbase = g * 128;
    int tid = threadIdx.x;
    int tx = tid & 15, ty = tid >> 4;

    float acc[8][8] = {};

    for (int kt = 0; kt < NKT; ++kt) {
        int k0 = kt * KT;
        for (int idx = tid; idx < 128 * KT; idx += 256) {
            int r = idx & 127;
            int k = idx >> 7;
            int row = row0 + r;
            As[k][r] = (row < N) ? x[(size_t)row * NF + k0 + k] : 0.0f;
        }
        for (int idx = tid; idx < KT * 32; idx += 256) {
            int k = idx >> 5;
            int c4 = (idx & 31) * 4;
            *(float4*)&Bs[k][c4] =
                *(const float4*)&Wc[(size_t)(k0 + k) * NCOLS + colbase + c4];
        }
        __syncthreads();
#pragma unroll
        for (int kk = 0; kk < KT; ++kk) {
            float4 a0 = *(const float4*)&As[kk][ty * 4];
            float4 a1 = *(const float4*)&As[kk][64 + ty * 4];
            float4 b0 = *(const float4*)&Bs[kk][tx * 4];
            float4 b1 = *(const float4*)&Bs[kk][64 + tx * 4];
            float av[8] = {a0.x, a0.y, a0.z, a0.w, a1.x, a1.y, a1.z, a1.w};
            float bv[8] = {b0.x, b0.y, b0.z, b0.w, b1.x, b1.y, b1.z, b1.w};
#pragma unroll
            for (int i = 0; i < 8; ++i)
#pragma unroll
                for (int j = 0; j < 8; ++j)
                    acc[i][j] += av[i] * bv[j];
        }
        __syncthreads();
    }

    // epilogue: rows {row0+ty*4+i, row0+64+ty*4+i}, cols {tx*4.., 64+tx*4..}
#pragma unroll
    for (int ih = 0; ih < 2; ++ih) {
#pragma unroll
        for (int i = 0; i < 4; ++i) {
            int row = row0 + ih * 64 + ty * 4 + i;
            if (row >= N) continue;
#pragma unroll
            for (int jh = 0; jh < 2; ++jh) {
                int cc = jh * 64 + tx * 4;
                float r0 = acc[ih * 4 + i][jh * 4 + 0];
                float r1 = acc[ih * 4 + i][jh * 4 + 1];
                float r2 = acc[ih * 4 + i][jh * 4 + 2];
                float r3 = acc[ih * 4 + i][jh * 4 + 3];
                if (g == 2) {
                    uint2 pk;
                    pk.x = (unsigned int)f2bf(r0) | ((unsigned int)f2bf(r1) << 16);
                    pk.y = (unsigned int)f2bf(r2) | ((unsigned int)f2bf(r3) << 16);
                    *(uint2*)(wb + (size_t)row * 64 + cc / 2) = pk;
                } else {
                    float* dst = (g == 0) ? u : s;
                    float4 v = {r0, r1, r2, r3};
                    *(float4*)(dst + (size_t)row * NH + cc) = v;
                }
            }
        }
    }
}

// prop1: sb[r] (bf16) = s[r] + 2 * sum nrm * wb[col]   (bf16 gather, f32 accum)
__global__ __launch_bounds__(256) void k_prop_b2b(
        const int* __restrict__ off, const int* __restrict__ scol,
        const float* __restrict__ snrm, const unsigned int* __restrict__ srcb,
        const float* __restrict__ add, unsigned int* __restrict__ dstb, int N) {
    int wid = (blockIdx.x * 256 + threadIdx.x) >> 6;
    if (wid >= N) return;
    int lane = threadIdx.x & 63;
    int e0 = off[wid], e1 = off[wid + 1];
    float a0 = 0.0f, a1 = 0.0f, b0 = 0.0f, b1 = 0.0f;
    int e = e0;
    for (; e + 2 <= e1; e += 2) {
        int c0 = scol[e];
        int c1 = scol[e + 1];
        float n0 = snrm[e];
        float n1 = snrm[e + 1];
        unsigned int v0 = srcb[(size_t)c0 * 64 + lane];
        unsigned int v1 = srcb[(size_t)c1 * 64 + lane];
        a0 += n0 * bf2f_lo(v0); a1 += n0 * bf2f_hi(v0);
        b0 += n1 * bf2f_lo(v1); b1 += n1 * bf2f_hi(v1);
    }
    if (e < e1) {
        int c0 = scol[e];
        float n0 = snrm[e];
        unsigned int v0 = srcb[(size_t)c0 * 64 + lane];
        a0 += n0 * bf2f_lo(v0); a1 += n0 * bf2f_hi(v0);
    }
    a0 = 2.0f * (a0 + b0);
    a1 = 2.0f * (a1 + b1);
    float2 ad = *(const float2*)(add + (size_t)wid * NH + lane * 2);
    unsigned int pk = (unsigned int)f2bf(ad.x + a0)
                    | ((unsigned int)f2bf(ad.y + a1) << 16);
    dstb[(size_t)wid * 64 + lane] = pk;
}

// prop2: h[r] (f32) = relu(u[r] + sum nrm * sb[col] + b1)
__global__ __launch_bounds__(256) void k_prop_b2f_relu(
        const int* __restrict__ off, const int* __restrict__ scol,
        const float* __restrict__ snrm, const unsigned int* __restrict__ srcb,
        const float* __restrict__ add, const float* __restrict__ b1,
        float* __restrict__ h, int N) {
    int wid = (blockIdx.x * 256 + threadIdx.x) >> 6;
    if (wid >= N) return;
    int lane = threadIdx.x & 63;
    int e0 = off[wid], e1 = off[wid + 1];
    float a0 = 0.0f, a1 = 0.0f, b0 = 0.0f, b1v = 0.0f;
    int e = e0;
    for (; e + 2 <= e1; e += 2) {
        int c0 = scol[e];
        int c1 = scol[e + 1];
        float n0 = snrm[e];
        float n1 = snrm[e + 1];
        unsigned int v0 = srcb[(size_t)c0 * 64 + lane];
        unsigned int v1 = srcb[(size_t)c1 * 64 + lane];
        a0 += n0 * bf2f_lo(v0); a1 += n0 * bf2f_hi(v0);
        b0 += n1 * bf2f_lo(v1); b1v += n1 * bf2f_hi(v1);
    }
    if (e < e1) {
        int c0 = scol[e];
        float n0 = snrm[e];
        unsigned int v0 = srcb[(size_t)c0 * 64 + lane];
        a0 += n0 * bf2f_lo(v0); a1 += n0 * bf2f_hi(v0);
    }
    a0 += b0; a1 += b1v;
    float2 ad = *(const float2*)(add + (size_t)wid * NH + lane * 2);
    float2 bb = *(const float2*)(b1 + lane * 2);
    float o0 = fmaxf(ad.x + a0 + bb.x, 0.0f);
    float o1 = fmaxf(ad.y + a1 + bb.y, 0.0f);
    float2 o = {o0, o1};
    *(float2*)(h + (size_t)wid * NH + lane * 2) = o;
}

// GEMM2: h[N,128] @ Wc2[128,8] -> out(+b2), s2, w2
__global__ __launch_bounds__(256) void k_gemm2(
        const float* __restrict__ h, const float* __restrict__ Wc2,
        const float* __restrict__ b2, float* __restrict__ out,
        float* __restrict__ s2, float* __restrict__ w2, int N) {
    __shared__ float Ws[128 * 8];
    int tid = threadIdx.x;
    for (int idx = tid; idx < 128 * 8; idx += 256) Ws[idx] = Wc2[idx];
    __syncthreads();

    int rl = tid >> 3;
    int sub = tid & 7;
    int row = blockIdx.x * 32 + rl;
    if (row >= N) return;

    float4 accA = {0, 0, 0, 0};
    float4 accB = {0, 0, 0, 0};
    const float4* hp = (const float4*)(h + (size_t)row * NH + sub * 16);
#pragma unroll
    for (int q = 0; q < 4; ++q) {
        float4 hv = hp[q];
        float he[4] = {hv.x, hv.y, hv.z, hv.w};
#pragma unroll
        for (int t = 0; t < 4; ++t) {
            int k = sub * 16 + q * 4 + t;
            float4 wa = *(const float4*)&Ws[k * 8 + 0];
            float4 wb = *(const float4*)&Ws[k * 8 + 4];
            accA.x += he[t] * wa.x; accA.y += he[t] * wa.y;
            accA.z += he[t] * wa.z; accA.w += he[t] * wa.w;
            accB.x += he[t] * wb.x; accB.y += he[t] * wb.y;
        }
    }
#pragma unroll
    for (int off = 4; off; off >>= 1) {
        accA.x += __shfl_xor(accA.x, off);
        accA.y += __shfl_xor(accA.y, off);
        accA.z += __shfl_xor(accA.z, off);
        accA.w += __shfl_xor(accA.w, off);
        accB.x += __shfl_xor(accB.x, off);
        accB.y += __shfl_xor(accB.y, off);
    }
    if (sub == 0) {
        out[(size_t)row * 2 + 0] = accA.x + b2[0];
        out[(size_t)row * 2 + 1] = accA.y + b2[1];
        s2[(size_t)row * 2 + 0] = accA.z;
        s2[(size_t)row * 2 + 1] = accA.w;
        w2[(size_t)row * 2 + 0] = accB.x;
        w2[(size_t)row * 2 + 1] = accB.y;
    }
}

// CSR prop, 2-wide: one thread per row.
__global__ __launch_bounds__(256) void k_prop2_csr(
        const int* __restrict__ off, const int* __restrict__ scol,
        const float* __restrict__ snrm, const float* __restrict__ src,
        const float* __restrict__ add, float* __restrict__ dst,
        float scale, int N) {
    int r = blockIdx.x * 256 + threadIdx.x;
    if (r >= N) return;
    int e0 = off[r], e1 = off[r + 1];
    float a0 = 0.0f, a1 = 0.0f;
    for (int e = e0; e < e1; ++e) {
        int c = scol[e];
        float nv = snrm[e];
        float2 v = *(const float2*)(src + (size_t)c * 2);
        a0 += nv * v.x;
        a1 += nv * v.y;
    }
    float2 ad = *(const float2*)(add + (size_t)r * 2);
    float2 o = {ad.x + scale * a0, ad.y + scale * a1};
    *(float2*)(dst + (size_t)r * 2) = o;
}

extern "C" void kernel_launch(void* const* d_in, const int* in_sizes, int n_in,
                              void* d_out, int out_size, void* d_ws, size_t ws_size,
                              hipStream_t stream) {
    const float* x   = (const float*)d_in[0];
    const int* eidx  = (const int*)d_in[1];
    const float* W1  = (const float*)d_in[2];
    const float* b1  = (const float*)d_in[3];
    const float* W2  = (const float*)d_in[4];
    const float* b2  = (const float*)d_in[5];
    float* out       = (float*)d_out;

    int N = in_sizes[0] / NF;
    int E = in_sizes[1] / 2;
    const int* erow = eidx;
    const int* ecol = eidx + E;

    char* p = (char*)d_ws;
    auto alloc = [&](size_t bytes) {
        char* q = p;
        p += (bytes + 255) & ~(size_t)255;
        return q;
    };
    float* u    = (float*)alloc((size_t)N * NH * 4);
    float* s    = (float*)alloc((size_t)N * NH * 4);
    float* h    = (float*)alloc((size_t)N * NH * 4);
    unsigned int* wb = (unsigned int*)alloc((size_t)N * 64 * 4);  // bf16 x 128
    unsigned int* sb = (unsigned int*)alloc((size_t)N * 64 * 4);  // bf16 x 128
    float* dis  = (float*)alloc((size_t)N * 4);
    int* cnt    = (int*)alloc((size_t)N * 4);
    int* off    = (int*)alloc((size_t)(N + 1) * 4);
    int* cur    = (int*)alloc((size_t)N * 4);
    int* bsum   = (int*)alloc((size_t)256 * 4);
    int* scol   = (int*)alloc((size_t)E * 4);
    float* snrm = (float*)alloc((size_t)E * 4);
    float* Wc1  = (float*)alloc((size_t)NF * NCOLS * 4);
    float* Wc2  = (float*)alloc((size_t)128 * 8 * 4);
    float* s2   = (float*)alloc((size_t)N * 2 * 4);
    float* w2   = (float*)alloc((size_t)N * 2 * 4);

    hipMemsetAsync(cnt, 0, (size_t)N * 4, stream);

    int gE = (E + 255) / 256;
    int gN = (N + 255) / 256;
    int NB = (N + 1023) / 1024;

    // CSR build
    k_count<<<gE, 256, 0, stream>>>(erow, cnt, E);
    k_dis<<<gN, 256, 0, stream>>>(cnt, dis, N);
    k_scan1<<<NB, 256, 0, stream>>>(cnt, off, bsum, N);
    k_scan2<<<1, 256, 0, stream>>>(bsum, NB);
    k_scan3<<<gN, 256, 0, stream>>>(off, cur, bsum, N, E);
    k_scatter<<<gE, 256, 0, stream>>>(erow, ecol, dis, cur, scol, snrm, E);

    // weights
    k_wc1<<<(NF * NCOLS + 255) / 256, 256, 0, stream>>>(W1, Wc1);
    k_wc2<<<4, 256, 0, stream>>>(W2, Wc2);

    // layer 1
    dim3 g1((N + 127) / 128, 3);
    k_gemm1<<<g1, 256, 0, stream>>>(x, Wc1, u, s, wb, N);

    int gW = (N * 64 + 255) / 256;   // one wave per row
    // sb = bf16( s + 2*prop(wb) )
    k_prop_b2b<<<gW, 256, 0, stream>>>(off, scol, snrm, wb, s, sb, N);
    // h = relu( u + prop(sb) + b1 )
    k_prop_b2f_relu<<<gW, 256, 0, stream>>>(off, scol, snrm, sb, u, b1, h, N);

    // layer 2
    k_gemm2<<<(N + 31) / 32, 256, 0, stream>>>(h, Wc2, b2, out, s2, w2, N);
    k_prop2_csr<<<gN, 256, 0, stream>>>(off, scol, snrm, w2, s2, s2, 2.0f, N);
    k_prop2_csr<<<gN, 256, 0, stream>>>(off, scol, snrm, s2, out, out, 1.0f, N);
}

// Round 6
// 1152.172 us; speedup vs baseline: 1.6877x; 1.3828x over previous
//
#include <hip/hip_runtime.h>
#include <hip/hip_bf16.h>
#include <stdint.h>

#define NF 165
#define NH 128
#define KP 192          // padded K for MFMA
#define NCOLS 384

typedef __attribute__((ext_vector_type(8))) short bf16x8;
typedef __attribute__((ext_vector_type(4))) float f32x4;

// ---- bf16 helpers --------------------------------------------------------

__device__ __forceinline__ unsigned short f2bf(float f) {
    unsigned int u = __builtin_bit_cast(unsigned int, f);
    u = (u + 0x7FFFu + ((u >> 16) & 1u)) >> 16;   // RNE
    return (unsigned short)u;
}
__device__ __forceinline__ float bf2f_lo(unsigned int v) {
    return __builtin_bit_cast(float, v << 16);
}
__device__ __forceinline__ float bf2f_hi(unsigned int v) {
    return __builtin_bit_cast(float, v & 0xFFFF0000u);
}

// ---- CSR build ----------------------------------------------------------

__global__ __launch_bounds__(256) void k_count(
        const int* __restrict__ erow, int* __restrict__ cnt, int E) {
    int e = blockIdx.x * 256 + threadIdx.x;
    if (e >= E) return;
    atomicAdd(&cnt[erow[e]], 1);
}

__global__ __launch_bounds__(256) void k_dis(
        const int* __restrict__ cnt, float* __restrict__ dis, int N) {
    int i = blockIdx.x * 256 + threadIdx.x;
    if (i >= N) return;
    int d = cnt[i];
    dis[i] = (d > 0) ? rsqrtf((float)d) : 0.0f;
}

__global__ __launch_bounds__(256) void k_scan1(
        const int* __restrict__ cnt, int* __restrict__ off,
        int* __restrict__ bsum, int N) {
    __shared__ int sh[256];
    int t = threadIdx.x;
    int base = blockIdx.x * 1024 + t * 4;
    int v0 = (base + 0 < N) ? cnt[base + 0] : 0;
    int v1 = (base + 1 < N) ? cnt[base + 1] : 0;
    int v2 = (base + 2 < N) ? cnt[base + 2] : 0;
    int v3 = (base + 3 < N) ? cnt[base + 3] : 0;
    int tsum = v0 + v1 + v2 + v3;
    sh[t] = tsum;
    __syncthreads();
#pragma unroll
    for (int ofs = 1; ofs < 256; ofs <<= 1) {
        int x = (t >= ofs) ? sh[t - ofs] : 0;
        __syncthreads();
        sh[t] += x;
        __syncthreads();
    }
    int excl = sh[t] - tsum;
    if (t == 255) bsum[blockIdx.x] = sh[t];
    if (base + 0 < N) off[base + 0] = excl;
    excl += v0;
    if (base + 1 < N) off[base + 1] = excl;
    excl += v1;
    if (base + 2 < N) off[base + 2] = excl;
    excl += v2;
    if (base + 3 < N) off[base + 3] = excl;
}

__global__ __launch_bounds__(256) void k_scan2(int* __restrict__ bsum, int NB) {
    __shared__ int sh[256];
    int t = threadIdx.x;
    int v = (t < NB) ? bsum[t] : 0;
    sh[t] = v;
    __syncthreads();
#pragma unroll
    for (int ofs = 1; ofs < 256; ofs <<= 1) {
        int x = (t >= ofs) ? sh[t - ofs] : 0;
        __syncthreads();
        sh[t] += x;
        __syncthreads();
    }
    if (t < NB) bsum[t] = sh[t] - v;
}

__global__ __launch_bounds__(256) void k_scan3(
        int* __restrict__ off, int* __restrict__ cur,
        const int* __restrict__ bsum, int N, int E) {
    int i = blockIdx.x * 256 + threadIdx.x;
    if (i >= N) return;
    int v = off[i] + bsum[i >> 10];
    off[i] = v;
    cur[i] = v;
    if (i == 0) off[N] = E;
}

__global__ __launch_bounds__(256) void k_scatter(
        const int* __restrict__ erow, const int* __restrict__ ecol,
        const float* __restrict__ dis, int* __restrict__ cur,
        int* __restrict__ scol, float* __restrict__ snrm, int E) {
    int e = blockIdx.x * 256 + threadIdx.x;
    if (e >= E) return;
    int r = erow[e];
    int c = ecol[e];
    int pos = atomicAdd(&cur[r], 1);
    scol[pos] = c;
    snrm[pos] = -dis[r] * dis[c];
}

// ---- conversions ---------------------------------------------------------

// x[N][165] f32 -> xb[N][192] bf16 (zero-padded)
__global__ __launch_bounds__(256) void k_xb(
        const float* __restrict__ x, unsigned short* __restrict__ xb, int N) {
    int gid = blockIdx.x * 256 + threadIdx.x;   // one per 8 outputs
    if (gid >= N * (KP / 8)) return;
    int row = gid / (KP / 8);
    int k0 = (gid % (KP / 8)) * 8;
    unsigned short v[8];
#pragma unroll
    for (int i = 0; i < 8; ++i) {
        int k = k0 + i;
        v[i] = (k < NF) ? f2bf(x[(size_t)row * NF + k]) : (unsigned short)0;
    }
    uint4 pk;
    pk.x = (unsigned)v[0] | ((unsigned)v[1] << 16);
    pk.y = (unsigned)v[2] | ((unsigned)v[3] << 16);
    pk.z = (unsigned)v[4] | ((unsigned)v[5] << 16);
    pk.w = (unsigned)v[6] | ((unsigned)v[7] << 16);
    *(uint4*)(xb + (size_t)row * KP + k0) = pk;
}

// W1[3][165][128] -> wbt[384][192] bf16, transposed & combined:
// col<128: W1[0]-W1[2]; col<256: W1[1]; else W1[2]. k padded to 192.
__global__ __launch_bounds__(256) void k_wbt(
        const float* __restrict__ W1, unsigned short* __restrict__ wbt) {
    int gid = blockIdx.x * 256 + threadIdx.x;
    if (gid >= NCOLS * (KP / 8)) return;
    int col = gid / (KP / 8);
    int k0 = (gid % (KP / 8)) * 8;
    int cc = col & 127;
    unsigned short v[8];
#pragma unroll
    for (int i = 0; i < 8; ++i) {
        int k = k0 + i;
        float f = 0.0f;
        if (k < NF) {
            if (col < 128)      f = W1[k * 128 + cc] - W1[42240 + k * 128 + cc];
            else if (col < 256) f = W1[21120 + k * 128 + cc];
            else                f = W1[42240 + k * 128 + cc];
        }
        v[i] = f2bf(f);
    }
    uint4 pk;
    pk.x = (unsigned)v[0] | ((unsigned)v[1] << 16);
    pk.y = (unsigned)v[2] | ((unsigned)v[3] << 16);
    pk.z = (unsigned)v[4] | ((unsigned)v[5] << 16);
    pk.w = (unsigned)v[6] | ((unsigned)v[7] << 16);
    *(uint4*)(wbt + (size_t)col * KP + k0) = pk;
}

// Wc2[128][8], k permuted to h's interleaved layout:
// h_lin[2c] = col c, h_lin[2c+1] = col c+64.
__global__ __launch_bounds__(256) void k_wc2(const float* __restrict__ W2,
                                             float* __restrict__ Wc2) {
    int gid = blockIdx.x * 256 + threadIdx.x;
    if (gid >= 128 * 8) return;
    int k = gid >> 3;
    int c = gid & 7;
    int ko = (k & 1) ? (k >> 1) + 64 : (k >> 1);   // original hidden index
    float v = 0.0f;
    if (c < 2)      v = W2[ko * 2 + c] - W2[512 + ko * 2 + c];
    else if (c < 4) v = W2[256 + ko * 2 + (c - 2)];
    else if (c < 6) v = W2[512 + ko * 2 + (c - 4)];
    Wc2[gid] = v;
}

// ---- GEMM1 via MFMA ------------------------------------------------------
// xb[N][192] @ wbt^T -> per col-group g: u2 (f32x2 interleaved) | s2f | wb (bf16 pairs)
// 128 rows x 128 cols per block; 4 waves, each 32 rows x 128 cols.
__global__ __launch_bounds__(256) void k_gemm1_mfma(
        const unsigned short* __restrict__ xb, const unsigned short* __restrict__ wbt,
        float2* __restrict__ u2, float2* __restrict__ s2f,
        unsigned int* __restrict__ wb, int N) {
    __shared__ unsigned short As[128][40];   // +8 pad: conflict-free b128 reads
    __shared__ unsigned short Bs[128][40];

    int tid = threadIdx.x;
    int w = tid >> 6;
    int lane = tid & 63;
    int l15 = lane & 15;
    int l16 = lane >> 4;
    int brow = blockIdx.x * 128;
    int g = blockIdx.y;
    int gcol = g * 128;

    int sr = tid >> 1;          // staging row 0..127
    int sk = (tid & 1) * 16;    // staging k-offset (ushorts)

    f32x4 acc[2][8] = {};

    for (int kc = 0; kc < 6; ++kc) {
        int k0 = kc * 32;
        uint4 va0 = {0, 0, 0, 0}, va1 = {0, 0, 0, 0};
        if (brow + sr < N) {
            const unsigned short* asrc = xb + (size_t)(brow + sr) * KP + k0 + sk;
            va0 = *(const uint4*)asrc;
            va1 = *(const uint4*)(asrc + 8);
        }
        const unsigned short* bsrc = wbt + (size_t)(gcol + sr) * KP + k0 + sk;
        uint4 vb0 = *(const uint4*)bsrc;
        uint4 vb1 = *(const uint4*)(bsrc + 8);
        __syncthreads();   // protect previous iteration's reads
        *(uint4*)&As[sr][sk] = va0;
        *(uint4*)&As[sr][sk + 8] = va1;
        *(uint4*)&Bs[sr][sk] = vb0;
        *(uint4*)&Bs[sr][sk + 8] = vb1;
        __syncthreads();

        bf16x8 a[2], b[8];
#pragma unroll
        for (int m = 0; m < 2; ++m)
            a[m] = *(const bf16x8*)&As[w * 32 + m * 16 + l15][l16 * 8];
#pragma unroll
        for (int n = 0; n < 8; ++n)
            b[n] = *(const bf16x8*)&Bs[n * 16 + l15][l16 * 8];
#pragma unroll
        for (int m = 0; m < 2; ++m)
#pragma unroll
            for (int n = 0; n < 8; ++n)
                acc[m][n] = __builtin_amdgcn_mfma_f32_16x16x32_bf16(
                    a[m], b[n], acc[m][n], 0, 0, 0);
    }

    // epilogue: lane holds cols {16n+l15} paired with {16n+l15+64}
#pragma unroll
    for (int m = 0; m < 2; ++m) {
#pragma unroll
        for (int reg = 0; reg < 4; ++reg) {
            int row = brow + w * 32 + m * 16 + l16 * 4 + reg;
            if (row >= N) continue;
#pragma unroll
            for (int n = 0; n < 4; ++n) {
                int c = n * 16 + l15;
                float lo = acc[m][n][reg];
                float hi = acc[m][n + 4][reg];
                if (g == 2) {
                    wb[(size_t)row * 64 + c] =
                        (unsigned)f2bf(lo) | ((unsigned)f2bf(hi) << 16);
                } else {
                    float2* dst = (g == 0) ? u2 : s2f;
                    float2 o; o.x = lo; o.y = hi;
                    dst[(size_t)row * 64 + c] = o;
                }
            }
        }
    }
}

// prop1: sb[r] (bf16) = s[r] + 2 * sum nrm * wb[col]   (bf16 gather, f32 accum)
__global__ __launch_bounds__(256) void k_prop_b2b(
        const int* __restrict__ off, const int* __restrict__ scol,
        const float* __restrict__ snrm, const unsigned int* __restrict__ srcb,
        const float* __restrict__ add, unsigned int* __restrict__ dstb, int N) {
    int wid = (blockIdx.x * 256 + threadIdx.x) >> 6;
    if (wid >= N) return;
    int lane = threadIdx.x & 63;
    int e0 = off[wid], e1 = off[wid + 1];
    float a0 = 0.0f, a1 = 0.0f, b0 = 0.0f, b1 = 0.0f;
    int e = e0;
    for (; e + 2 <= e1; e += 2) {
        int c0 = scol[e];
        int c1 = scol[e + 1];
        float n0 = snrm[e];
        float n1 = snrm[e + 1];
        unsigned int v0 = srcb[(size_t)c0 * 64 + lane];
        unsigned int v1 = srcb[(size_t)c1 * 64 + lane];
        a0 += n0 * bf2f_lo(v0); a1 += n0 * bf2f_hi(v0);
        b0 += n1 * bf2f_lo(v1); b1 += n1 * bf2f_hi(v1);
    }
    if (e < e1) {
        int c0 = scol[e];
        float n0 = snrm[e];
        unsigned int v0 = srcb[(size_t)c0 * 64 + lane];
        a0 += n0 * bf2f_lo(v0); a1 += n0 * bf2f_hi(v0);
    }
    a0 = 2.0f * (a0 + b0);
    a1 = 2.0f * (a1 + b1);
    float2 ad = *(const float2*)(add + (size_t)wid * NH + lane * 2);
    unsigned int pk = (unsigned int)f2bf(ad.x + a0)
                    | ((unsigned int)f2bf(ad.y + a1) << 16);
    dstb[(size_t)wid * 64 + lane] = pk;
}

// prop2: h[r] (f32) = relu(u[r] + sum nrm * sb[col] + b1)  [in-place safe: h==u ok]
__global__ __launch_bounds__(256) void k_prop_b2f_relu(
        const int* __restrict__ off, const int* __restrict__ scol,
        const float* __restrict__ snrm, const unsigned int* __restrict__ srcb,
        const float* __restrict__ add, const float* __restrict__ b1,
        float* __restrict__ h, int N) {
    int wid = (blockIdx.x * 256 + threadIdx.x) >> 6;
    if (wid >= N) return;
    int lane = threadIdx.x & 63;
    int e0 = off[wid], e1 = off[wid + 1];
    float a0 = 0.0f, a1 = 0.0f, b0 = 0.0f, b1v = 0.0f;
    int e = e0;
    for (; e + 2 <= e1; e += 2) {
        int c0 = scol[e];
        int c1 = scol[e + 1];
        float n0 = snrm[e];
        float n1 = snrm[e + 1];
        unsigned int v0 = srcb[(size_t)c0 * 64 + lane];
        unsigned int v1 = srcb[(size_t)c1 * 64 + lane];
        a0 += n0 * bf2f_lo(v0); a1 += n0 * bf2f_hi(v0);
        b0 += n1 * bf2f_lo(v1); b1v += n1 * bf2f_hi(v1);
    }
    if (e < e1) {
        int c0 = scol[e];
        float n0 = snrm[e];
        unsigned int v0 = srcb[(size_t)c0 * 64 + lane];
        a0 += n0 * bf2f_lo(v0); a1 += n0 * bf2f_hi(v0);
    }
    a0 += b0; a1 += b1v;
    float2 ad = *(const float2*)(add + (size_t)wid * NH + lane * 2);
    float bx = b1[lane];            // interleaved layout: (c, c+64)
    float by = b1[lane + 64];
    float o0 = fmaxf(ad.x + a0 + bx, 0.0f);
    float o1 = fmaxf(ad.y + a1 + by, 0.0f);
    float2 o = {o0, o1};
    *(float2*)(h + (size_t)wid * NH + lane * 2) = o;
}

// GEMM2: h[N,128] (interleaved layout) @ Wc2[128,8] -> out(+b2), s2, w2
__global__ __launch_bounds__(256) void k_gemm2(
        const float* __restrict__ h, const float* __restrict__ Wc2,
        const float* __restrict__ b2, float* __restrict__ out,
        float* __restrict__ s2, float* __restrict__ w2, int N) {
    __shared__ float Ws[128 * 8];
    int tid = threadIdx.x;
    for (int idx = tid; idx < 128 * 8; idx += 256) Ws[idx] = Wc2[idx];
    __syncthreads();

    int rl = tid >> 3;
    int sub = tid & 7;
    int row = blockIdx.x * 32 + rl;
    if (row >= N) return;

    float4 accA = {0, 0, 0, 0};
    float4 accB = {0, 0, 0, 0};
    const float4* hp = (const float4*)(h + (size_t)row * NH + sub * 16);
#pragma unroll
    for (int q = 0; q < 4; ++q) {
        float4 hv = hp[q];
        float he[4] = {hv.x, hv.y, hv.z, hv.w};
#pragma unroll
        for (int t = 0; t < 4; ++t) {
            int k = sub * 16 + q * 4 + t;
            float4 wa = *(const float4*)&Ws[k * 8 + 0];
            float4 wbv = *(const float4*)&Ws[k * 8 + 4];
            accA.x += he[t] * wa.x; accA.y += he[t] * wa.y;
            accA.z += he[t] * wa.z; accA.w += he[t] * wa.w;
            accB.x += he[t] * wbv.x; accB.y += he[t] * wbv.y;
        }
    }
#pragma unroll
    for (int off = 4; off; off >>= 1) {
        accA.x += __shfl_xor(accA.x, off);
        accA.y += __shfl_xor(accA.y, off);
        accA.z += __shfl_xor(accA.z, off);
        accA.w += __shfl_xor(accA.w, off);
        accB.x += __shfl_xor(accB.x, off);
        accB.y += __shfl_xor(accB.y, off);
    }
    if (sub == 0) {
        out[(size_t)row * 2 + 0] = accA.x + b2[0];
        out[(size_t)row * 2 + 1] = accA.y + b2[1];
        s2[(size_t)row * 2 + 0] = accA.z;
        s2[(size_t)row * 2 + 1] = accA.w;
        w2[(size_t)row * 2 + 0] = accB.x;
        w2[(size_t)row * 2 + 1] = accB.y;
    }
}

// CSR prop, 2-wide: one thread per row.
__global__ __launch_bounds__(256) void k_prop2_csr(
        const int* __restrict__ off, const int* __restrict__ scol,
        const float* __restrict__ snrm, const float* __restrict__ src,
        const float* __restrict__ add, float* __restrict__ dst,
        float scale, int N) {
    int r = blockIdx.x * 256 + threadIdx.x;
    if (r >= N) return;
    int e0 = off[r], e1 = off[r + 1];
    float a0 = 0.0f, a1 = 0.0f;
    for (int e = e0; e < e1; ++e) {
        int c = scol[e];
        float nv = snrm[e];
        float2 v = *(const float2*)(src + (size_t)c * 2);
        a0 += nv * v.x;
        a1 += nv * v.y;
    }
    float2 ad = *(const float2*)(add + (size_t)r * 2);
    float2 o = {ad.x + scale * a0, ad.y + scale * a1};
    *(float2*)(dst + (size_t)r * 2) = o;
}

extern "C" void kernel_launch(void* const* d_in, const int* in_sizes, int n_in,
                              void* d_out, int out_size, void* d_ws, size_t ws_size,
                              hipStream_t stream) {
    const float* x   = (const float*)d_in[0];
    const int* eidx  = (const int*)d_in[1];
    const float* W1  = (const float*)d_in[2];
    const float* b1  = (const float*)d_in[3];
    const float* W2  = (const float*)d_in[4];
    const float* b2  = (const float*)d_in[5];
    float* out       = (float*)d_out;

    int N = in_sizes[0] / NF;
    int E = in_sizes[1] / 2;
    const int* erow = eidx;
    const int* ecol = eidx + E;

    char* p = (char*)d_ws;
    auto alloc = [&](size_t bytes) {
        char* q = p;
        p += (bytes + 255) & ~(size_t)255;
        return q;
    };
    float* u    = (float*)alloc((size_t)N * NH * 4);        // layer-1 T0 combo; reused as h
    float* s    = (float*)alloc((size_t)N * NH * 4);        // layer-1 T1 combo
    unsigned int* wb = (unsigned int*)alloc((size_t)N * 64 * 4);  // bf16 pairs
    unsigned int* sb = (unsigned int*)alloc((size_t)N * 64 * 4);  // bf16 pairs
    unsigned short* xb  = (unsigned short*)alloc((size_t)N * KP * 2);
    unsigned short* wbt = (unsigned short*)alloc((size_t)NCOLS * KP * 2);
    float* dis  = (float*)alloc((size_t)N * 4);
    int* cnt    = (int*)alloc((size_t)N * 4);
    int* off    = (int*)alloc((size_t)(N + 1) * 4);
    int* cur    = (int*)alloc((size_t)N * 4);
    int* bsum   = (int*)alloc((size_t)256 * 4);
    int* scol   = (int*)alloc((size_t)E * 4);
    float* snrm = (float*)alloc((size_t)E * 4);
    float* Wc2  = (float*)alloc((size_t)128 * 8 * 4);
    float* s2   = (float*)alloc((size_t)N * 2 * 4);
    float* w2   = (float*)alloc((size_t)N * 2 * 4);

    hipMemsetAsync(cnt, 0, (size_t)N * 4, stream);

    int gE = (E + 255) / 256;
    int gN = (N + 255) / 256;
    int NB = (N + 1023) / 1024;

    // conversions
    k_xb<<<(N * (KP / 8) + 255) / 256, 256, 0, stream>>>(x, xb, N);
    k_wbt<<<(NCOLS * (KP / 8) + 255) / 256, 256, 0, stream>>>(W1, wbt);
    k_wc2<<<4, 256, 0, stream>>>(W2, Wc2);

    // CSR build
    k_count<<<gE, 256, 0, stream>>>(erow, cnt, E);
    k_dis<<<gN, 256, 0, stream>>>(cnt, dis, N);
    k_scan1<<<NB, 256, 0, stream>>>(cnt, off, bsum, N);
    k_scan2<<<1, 256, 0, stream>>>(bsum, NB);
    k_scan3<<<gN, 256, 0, stream>>>(off, cur, bsum, N, E);
    k_scatter<<<gE, 256, 0, stream>>>(erow, ecol, dis, cur, scol, snrm, E);

    // layer 1: MFMA GEMM
    dim3 g1((N + 127) / 128, 3);
    k_gemm1_mfma<<<g1, 256, 0, stream>>>(xb, wbt, (float2*)u, (float2*)s, wb, N);

    int gW = (N * 64 + 255) / 256;   // one wave per row
    // sb = bf16( s + 2*prop(wb) )
    k_prop_b2b<<<gW, 256, 0, stream>>>(off, scol, snrm, wb, s, sb, N);
    // h(=u) = relu( u + prop(sb) + b1 )   [in-place: reads/writes same row only]
    k_prop_b2f_relu<<<gW, 256, 0, stream>>>(off, scol, snrm, sb, u, b1, u, N);

    // layer 2
    k_gemm2<<<(N + 31) / 32, 256, 0, stream>>>(u, Wc2, b2, out, s2, w2, N);
    k_prop2_csr<<<gN, 256, 0, stream>>>(off, scol, snrm, w2, s2, s2, 2.0f, N);
    k_prop2_csr<<<gN, 256, 0, stream>>>(off, scol, snrm, s2, out, out, 1.0f, N);
}

// Round 7
// 881.037 us; speedup vs baseline: 2.2071x; 1.3077x over previous
//
#include <hip/hip_runtime.h>
#include <hip/hip_bf16.h>
#include <stdint.h>

#define NF 165
#define NH 128
#define KP 192          // padded K for MFMA
#define NCOLS 384

typedef __attribute__((ext_vector_type(8))) short bf16x8;
typedef __attribute__((ext_vector_type(4))) float f32x4;

// ---- bf16 helpers --------------------------------------------------------

__device__ __forceinline__ unsigned short f2bf(float f) {
    unsigned int u = __builtin_bit_cast(unsigned int, f);
    u = (u + 0x7FFFu + ((u >> 16) & 1u)) >> 16;   // RNE
    return (unsigned short)u;
}
__device__ __forceinline__ float bf2f_lo(unsigned int v) {
    return __builtin_bit_cast(float, v << 16);
}
__device__ __forceinline__ float bf2f_hi(unsigned int v) {
    return __builtin_bit_cast(float, v & 0xFFFF0000u);
}

// ---- CSR build ----------------------------------------------------------

__global__ __launch_bounds__(256) void k_count(
        const int* __restrict__ erow, int* __restrict__ cnt, int E) {
    int e = blockIdx.x * 256 + threadIdx.x;
    if (e >= E) return;
    atomicAdd(&cnt[erow[e]], 1);
}

__global__ __launch_bounds__(256) void k_dis(
        const int* __restrict__ cnt, float* __restrict__ dis, int N) {
    int i = blockIdx.x * 256 + threadIdx.x;
    if (i >= N) return;
    int d = cnt[i];
    dis[i] = (d > 0) ? rsqrtf((float)d) : 0.0f;
}

__global__ __launch_bounds__(256) void k_scan1(
        const int* __restrict__ cnt, int* __restrict__ off,
        int* __restrict__ bsum, int N) {
    __shared__ int sh[256];
    int t = threadIdx.x;
    int base = blockIdx.x * 1024 + t * 4;
    int v0 = (base + 0 < N) ? cnt[base + 0] : 0;
    int v1 = (base + 1 < N) ? cnt[base + 1] : 0;
    int v2 = (base + 2 < N) ? cnt[base + 2] : 0;
    int v3 = (base + 3 < N) ? cnt[base + 3] : 0;
    int tsum = v0 + v1 + v2 + v3;
    sh[t] = tsum;
    __syncthreads();
#pragma unroll
    for (int ofs = 1; ofs < 256; ofs <<= 1) {
        int x = (t >= ofs) ? sh[t - ofs] : 0;
        __syncthreads();
        sh[t] += x;
        __syncthreads();
    }
    int excl = sh[t] - tsum;
    if (t == 255) bsum[blockIdx.x] = sh[t];
    if (base + 0 < N) off[base + 0] = excl;
    excl += v0;
    if (base + 1 < N) off[base + 1] = excl;
    excl += v1;
    if (base + 2 < N) off[base + 2] = excl;
    excl += v2;
    if (base + 3 < N) off[base + 3] = excl;
}

__global__ __launch_bounds__(256) void k_scan2(int* __restrict__ bsum, int NB) {
    __shared__ int sh[256];
    int t = threadIdx.x;
    int v = (t < NB) ? bsum[t] : 0;
    sh[t] = v;
    __syncthreads();
#pragma unroll
    for (int ofs = 1; ofs < 256; ofs <<= 1) {
        int x = (t >= ofs) ? sh[t - ofs] : 0;
        __syncthreads();
        sh[t] += x;
        __syncthreads();
    }
    if (t < NB) bsum[t] = sh[t] - v;
}

__global__ __launch_bounds__(256) void k_scan3(
        int* __restrict__ off, int* __restrict__ cur,
        const int* __restrict__ bsum, int N, int E) {
    int i = blockIdx.x * 256 + threadIdx.x;
    if (i >= N) return;
    int v = off[i] + bsum[i >> 10];
    off[i] = v;
    cur[i] = v;
    if (i == 0) off[N] = E;
}

// Scatter edges row-sorted; packed {col, nrm} 8B single store.
__global__ __launch_bounds__(256) void k_scatter(
        const int* __restrict__ erow, const int* __restrict__ ecol,
        const float* __restrict__ dis, int* __restrict__ cur,
        uint2* __restrict__ es, int E) {
    int e = blockIdx.x * 256 + threadIdx.x;
    if (e >= E) return;
    int r = erow[e];
    int c = ecol[e];
    int pos = atomicAdd(&cur[r], 1);
    uint2 v;
    v.x = (unsigned)c;
    v.y = __builtin_bit_cast(unsigned, -dis[r] * dis[c]);
    es[pos] = v;
}

// ---- conversions ---------------------------------------------------------

__global__ __launch_bounds__(256) void k_xb(
        const float* __restrict__ x, unsigned short* __restrict__ xb, int N) {
    int gid = blockIdx.x * 256 + threadIdx.x;
    if (gid >= N * (KP / 8)) return;
    int row = gid / (KP / 8);
    int k0 = (gid % (KP / 8)) * 8;
    unsigned short v[8];
#pragma unroll
    for (int i = 0; i < 8; ++i) {
        int k = k0 + i;
        v[i] = (k < NF) ? f2bf(x[(size_t)row * NF + k]) : (unsigned short)0;
    }
    uint4 pk;
    pk.x = (unsigned)v[0] | ((unsigned)v[1] << 16);
    pk.y = (unsigned)v[2] | ((unsigned)v[3] << 16);
    pk.z = (unsigned)v[4] | ((unsigned)v[5] << 16);
    pk.w = (unsigned)v[6] | ((unsigned)v[7] << 16);
    *(uint4*)(xb + (size_t)row * KP + k0) = pk;
}

__global__ __launch_bounds__(256) void k_wbt(
        const float* __restrict__ W1, unsigned short* __restrict__ wbt) {
    int gid = blockIdx.x * 256 + threadIdx.x;
    if (gid >= NCOLS * (KP / 8)) return;
    int col = gid / (KP / 8);
    int k0 = (gid % (KP / 8)) * 8;
    int cc = col & 127;
    unsigned short v[8];
#pragma unroll
    for (int i = 0; i < 8; ++i) {
        int k = k0 + i;
        float f = 0.0f;
        if (k < NF) {
            if (col < 128)      f = W1[k * 128 + cc] - W1[42240 + k * 128 + cc];
            else if (col < 256) f = W1[21120 + k * 128 + cc];
            else                f = W1[42240 + k * 128 + cc];
        }
        v[i] = f2bf(f);
    }
    uint4 pk;
    pk.x = (unsigned)v[0] | ((unsigned)v[1] << 16);
    pk.y = (unsigned)v[2] | ((unsigned)v[3] << 16);
    pk.z = (unsigned)v[4] | ((unsigned)v[5] << 16);
    pk.w = (unsigned)v[6] | ((unsigned)v[7] << 16);
    *(uint4*)(wbt + (size_t)col * KP + k0) = pk;
}

// Wc2[128][8] with k in interleaved-hidden layout: k_lin 2c->(c), 2c+1->(c+64)
__global__ __launch_bounds__(256) void k_wc2(const float* __restrict__ W2,
                                             float* __restrict__ Wc2) {
    int gid = blockIdx.x * 256 + threadIdx.x;
    if (gid >= 128 * 8) return;
    int k = gid >> 3;
    int c = gid & 7;
    int ko = (k & 1) ? (k >> 1) + 64 : (k >> 1);
    float v = 0.0f;
    if (c < 2)      v = W2[ko * 2 + c] - W2[512 + ko * 2 + c];
    else if (c < 4) v = W2[256 + ko * 2 + (c - 2)];
    else if (c < 6) v = W2[512 + ko * 2 + (c - 4)];
    Wc2[gid] = v;
}

// ---- GEMM1 via MFMA ------------------------------------------------------

__global__ __launch_bounds__(256) void k_gemm1_mfma(
        const unsigned short* __restrict__ xb, const unsigned short* __restrict__ wbt,
        float2* __restrict__ u2, float2* __restrict__ s2f,
        unsigned int* __restrict__ wb, int N) {
    __shared__ unsigned short As[128][40];
    __shared__ unsigned short Bs[128][40];

    int tid = threadIdx.x;
    int w = tid >> 6;
    int lane = tid & 63;
    int l15 = lane & 15;
    int l16 = lane >> 4;
    int brow = blockIdx.x * 128;
    int g = blockIdx.y;
    int gcol = g * 128;

    int sr = tid >> 1;
    int sk = (tid & 1) * 16;

    f32x4 acc[2][8] = {};

    for (int kc = 0; kc < 6; ++kc) {
        int k0 = kc * 32;
        uint4 va0 = {0, 0, 0, 0}, va1 = {0, 0, 0, 0};
        if (brow + sr < N) {
            const unsigned short* asrc = xb + (size_t)(brow + sr) * KP + k0 + sk;
            va0 = *(const uint4*)asrc;
            va1 = *(const uint4*)(asrc + 8);
        }
        const unsigned short* bsrc = wbt + (size_t)(gcol + sr) * KP + k0 + sk;
        uint4 vb0 = *(const uint4*)bsrc;
        uint4 vb1 = *(const uint4*)(bsrc + 8);
        __syncthreads();
        *(uint4*)&As[sr][sk] = va0;
        *(uint4*)&As[sr][sk + 8] = va1;
        *(uint4*)&Bs[sr][sk] = vb0;
        *(uint4*)&Bs[sr][sk + 8] = vb1;
        __syncthreads();

        bf16x8 a[2], b[8];
#pragma unroll
        for (int m = 0; m < 2; ++m)
            a[m] = *(const bf16x8*)&As[w * 32 + m * 16 + l15][l16 * 8];
#pragma unroll
        for (int n = 0; n < 8; ++n)
            b[n] = *(const bf16x8*)&Bs[n * 16 + l15][l16 * 8];
#pragma unroll
        for (int m = 0; m < 2; ++m)
#pragma unroll
            for (int n = 0; n < 8; ++n)
                acc[m][n] = __builtin_amdgcn_mfma_f32_16x16x32_bf16(
                    a[m], b[n], acc[m][n], 0, 0, 0);
    }

#pragma unroll
    for (int m = 0; m < 2; ++m) {
#pragma unroll
        for (int reg = 0; reg < 4; ++reg) {
            int row = brow + w * 32 + m * 16 + l16 * 4 + reg;
            if (row >= N) continue;
#pragma unroll
            for (int n = 0; n < 4; ++n) {
                int c = n * 16 + l15;
                float lo = acc[m][n][reg];
                float hi = acc[m][n + 4][reg];
                if (g == 2) {
                    wb[(size_t)row * 64 + c] =
                        (unsigned)f2bf(lo) | ((unsigned)f2bf(hi) << 16);
                } else {
                    float2* dst = (g == 0) ? u2 : s2f;
                    float2 o; o.x = lo; o.y = hi;
                    dst[(size_t)row * 64 + c] = o;
                }
            }
        }
    }
}

// ---- 128-wide props: 4 rows/wave, 16 lanes/row, uint4 gathers, unroll-2 ---

// sb[r] (bf16) = s[r] + 2 * sum nrm * wb[col]
__global__ __launch_bounds__(256) void k_prop_b2b(
        const int* __restrict__ off, const uint2* __restrict__ es,
        const unsigned int* __restrict__ srcb, const float2* __restrict__ add2,
        unsigned int* __restrict__ dstb, int N) {
    int wid = (blockIdx.x * 256 + threadIdx.x) >> 6;
    int lane = threadIdx.x & 63;
    int g = lane >> 4, q = lane & 15;
    int r = wid * 4 + g;
    if (r >= N) return;
    int e = off[r], end = off[r + 1];
    const uint4* src4 = (const uint4*)srcb;
    float a[8] = {}, b[8] = {};
    for (; e + 2 <= end; e += 2) {
        uint2 e0 = es[e], e1 = es[e + 1];
        float n0 = __builtin_bit_cast(float, e0.y);
        float n1 = __builtin_bit_cast(float, e1.y);
        uint4 v0 = src4[(size_t)e0.x * 16 + q];
        uint4 v1 = src4[(size_t)e1.x * 16 + q];
        unsigned vv0[4] = {v0.x, v0.y, v0.z, v0.w};
        unsigned vv1[4] = {v1.x, v1.y, v1.z, v1.w};
#pragma unroll
        for (int j = 0; j < 4; ++j) {
            a[2 * j] += n0 * bf2f_lo(vv0[j]); a[2 * j + 1] += n0 * bf2f_hi(vv0[j]);
            b[2 * j] += n1 * bf2f_lo(vv1[j]); b[2 * j + 1] += n1 * bf2f_hi(vv1[j]);
        }
    }
    if (e < end) {
        uint2 e0 = es[e];
        float n0 = __builtin_bit_cast(float, e0.y);
        uint4 v0 = src4[(size_t)e0.x * 16 + q];
        unsigned vv0[4] = {v0.x, v0.y, v0.z, v0.w};
#pragma unroll
        for (int j = 0; j < 4; ++j) {
            a[2 * j] += n0 * bf2f_lo(vv0[j]); a[2 * j + 1] += n0 * bf2f_hi(vv0[j]);
        }
    }
    uint4 o;
    unsigned* op = (unsigned*)&o;
#pragma unroll
    for (int j = 0; j < 4; ++j) {
        float2 ad = add2[(size_t)r * 64 + q * 4 + j];
        float lo = ad.x + 2.0f * (a[2 * j] + b[2 * j]);
        float hi = ad.y + 2.0f * (a[2 * j + 1] + b[2 * j + 1]);
        op[j] = (unsigned)f2bf(lo) | ((unsigned)f2bf(hi) << 16);
    }
    ((uint4*)dstb)[(size_t)r * 16 + q] = o;
}

// hb[r] (bf16) = relu(u[r] + sum nrm * sb[col] + b1)
__global__ __launch_bounds__(256) void k_prop_b2f_relu(
        const int* __restrict__ off, const uint2* __restrict__ es,
        const unsigned int* __restrict__ srcb, const float2* __restrict__ add2,
        const float* __restrict__ b1, unsigned int* __restrict__ hb, int N) {
    int wid = (blockIdx.x * 256 + threadIdx.x) >> 6;
    int lane = threadIdx.x & 63;
    int g = lane >> 4, q = lane & 15;
    int r = wid * 4 + g;
    if (r >= N) return;
    int e = off[r], end = off[r + 1];
    const uint4* src4 = (const uint4*)srcb;
    float a[8] = {}, b[8] = {};
    for (; e + 2 <= end; e += 2) {
        uint2 e0 = es[e], e1 = es[e + 1];
        float n0 = __builtin_bit_cast(float, e0.y);
        float n1 = __builtin_bit_cast(float, e1.y);
        uint4 v0 = src4[(size_t)e0.x * 16 + q];
        uint4 v1 = src4[(size_t)e1.x * 16 + q];
        unsigned vv0[4] = {v0.x, v0.y, v0.z, v0.w};
        unsigned vv1[4] = {v1.x, v1.y, v1.z, v1.w};
#pragma unroll
        for (int j = 0; j < 4; ++j) {
            a[2 * j] += n0 * bf2f_lo(vv0[j]); a[2 * j + 1] += n0 * bf2f_hi(vv0[j]);
            b[2 * j] += n1 * bf2f_lo(vv1[j]); b[2 * j + 1] += n1 * bf2f_hi(vv1[j]);
        }
    }
    if (e < end) {
        uint2 e0 = es[e];
        float n0 = __builtin_bit_cast(float, e0.y);
        uint4 v0 = src4[(size_t)e0.x * 16 + q];
        unsigned vv0[4] = {v0.x, v0.y, v0.z, v0.w};
#pragma unroll
        for (int j = 0; j < 4; ++j) {
            a[2 * j] += n0 * bf2f_lo(vv0[j]); a[2 * j + 1] += n0 * bf2f_hi(vv0[j]);
        }
    }
    uint4 o;
    unsigned* op = (unsigned*)&o;
#pragma unroll
    for (int j = 0; j < 4; ++j) {
        int c = q * 4 + j;
        float2 ad = add2[(size_t)r * 64 + c];
        float lo = fmaxf(ad.x + (a[2 * j] + b[2 * j]) + b1[c], 0.0f);
        float hi = fmaxf(ad.y + (a[2 * j + 1] + b[2 * j + 1]) + b1[c + 64], 0.0f);
        op[j] = (unsigned)f2bf(lo) | ((unsigned)f2bf(hi) << 16);
    }
    ((uint4*)hb)[(size_t)r * 16 + q] = o;
}

// GEMM2: hb[N,64] (bf16 pairs, interleaved) @ Wc2[128,8] -> out(+b2), s2, w2
__global__ __launch_bounds__(256) void k_gemm2(
        const unsigned int* __restrict__ hb, const float* __restrict__ Wc2,
        const float* __restrict__ b2, float* __restrict__ out,
        float* __restrict__ s2, float* __restrict__ w2, int N) {
    __shared__ float Ws[128 * 8];
    int tid = threadIdx.x;
    for (int idx = tid; idx < 128 * 8; idx += 256) Ws[idx] = Wc2[idx];
    __syncthreads();

    int rl = tid >> 3;
    int sub = tid & 7;
    int row = blockIdx.x * 32 + rl;
    if (row >= N) return;

    float4 accA = {0, 0, 0, 0};
    float4 accB = {0, 0, 0, 0};
    const uint4* hp = (const uint4*)(hb + (size_t)row * 64 + sub * 8);
#pragma unroll
    for (int qq = 0; qq < 2; ++qq) {
        uint4 hv = hp[qq];
        unsigned hu[4] = {hv.x, hv.y, hv.z, hv.w};
#pragma unroll
        for (int t = 0; t < 4; ++t) {
            int kl = sub * 16 + qq * 8 + 2 * t;
            float he0 = bf2f_lo(hu[t]);
            float he1 = bf2f_hi(hu[t]);
            const float* w0 = &Ws[kl * 8];
            const float* w1 = &Ws[(kl + 1) * 8];
            accA.x += he0 * w0[0] + he1 * w1[0];
            accA.y += he0 * w0[1] + he1 * w1[1];
            accA.z += he0 * w0[2] + he1 * w1[2];
            accA.w += he0 * w0[3] + he1 * w1[3];
            accB.x += he0 * w0[4] + he1 * w1[4];
            accB.y += he0 * w0[5] + he1 * w1[5];
        }
    }
#pragma unroll
    for (int off = 4; off; off >>= 1) {
        accA.x += __shfl_xor(accA.x, off);
        accA.y += __shfl_xor(accA.y, off);
        accA.z += __shfl_xor(accA.z, off);
        accA.w += __shfl_xor(accA.w, off);
        accB.x += __shfl_xor(accB.x, off);
        accB.y += __shfl_xor(accB.y, off);
    }
    if (sub == 0) {
        out[(size_t)row * 2 + 0] = accA.x + b2[0];
        out[(size_t)row * 2 + 1] = accA.y + b2[1];
        s2[(size_t)row * 2 + 0] = accA.z;
        s2[(size_t)row * 2 + 1] = accA.w;
        w2[(size_t)row * 2 + 0] = accB.x;
        w2[(size_t)row * 2 + 1] = accB.y;
    }
}

// CSR prop, 2-wide: one thread per row.
__global__ __launch_bounds__(256) void k_prop2_csr(
        const int* __restrict__ off, const uint2* __restrict__ es,
        const float* __restrict__ src, const float* __restrict__ add,
        float* __restrict__ dst, float scale, int N) {
    int r = blockIdx.x * 256 + threadIdx.x;
    if (r >= N) return;
    int e0 = off[r], e1 = off[r + 1];
    float a0 = 0.0f, a1 = 0.0f;
    for (int e = e0; e < e1; ++e) {
        uint2 ev = es[e];
        float nv = __builtin_bit_cast(float, ev.y);
        float2 v = *(const float2*)(src + (size_t)ev.x * 2);
        a0 += nv * v.x;
        a1 += nv * v.y;
    }
    float2 ad = *(const float2*)(add + (size_t)r * 2);
    float2 o = {ad.x + scale * a0, ad.y + scale * a1};
    *(float2*)(dst + (size_t)r * 2) = o;
}

extern "C" void kernel_launch(void* const* d_in, const int* in_sizes, int n_in,
                              void* d_out, int out_size, void* d_ws, size_t ws_size,
                              hipStream_t stream) {
    const float* x   = (const float*)d_in[0];
    const int* eidx  = (const int*)d_in[1];
    const float* W1  = (const float*)d_in[2];
    const float* b1  = (const float*)d_in[3];
    const float* W2  = (const float*)d_in[4];
    const float* b2  = (const float*)d_in[5];
    float* out       = (float*)d_out;

    int N = in_sizes[0] / NF;
    int E = in_sizes[1] / 2;
    const int* erow = eidx;
    const int* ecol = eidx + E;

    char* p = (char*)d_ws;
    auto alloc = [&](size_t bytes) {
        char* q = p;
        p += (bytes + 255) & ~(size_t)255;
        return q;
    };
    float* u    = (float*)alloc((size_t)N * NH * 4);
    float* s    = (float*)alloc((size_t)N * NH * 4);
    unsigned int* wb = (unsigned int*)alloc((size_t)N * 64 * 4);  // bf16 pairs; reused as hb
    unsigned int* sb = (unsigned int*)alloc((size_t)N * 64 * 4);
    unsigned short* xb  = (unsigned short*)alloc((size_t)N * KP * 2);
    unsigned short* wbt = (unsigned short*)alloc((size_t)NCOLS * KP * 2);
    float* dis  = (float*)alloc((size_t)N * 4);
    int* cnt    = (int*)alloc((size_t)N * 4);
    int* off    = (int*)alloc((size_t)(N + 1) * 4);
    int* cur    = (int*)alloc((size_t)N * 4);
    int* bsum   = (int*)alloc((size_t)256 * 4);
    uint2* es   = (uint2*)alloc((size_t)E * 8);
    float* Wc2  = (float*)alloc((size_t)128 * 8 * 4);
    float* s2   = (float*)alloc((size_t)N * 2 * 4);
    float* w2   = (float*)alloc((size_t)N * 2 * 4);

    hipMemsetAsync(cnt, 0, (size_t)N * 4, stream);

    int gE = (E + 255) / 256;
    int gN = (N + 255) / 256;
    int NB = (N + 1023) / 1024;

    // conversions
    k_xb<<<(N * (KP / 8) + 255) / 256, 256, 0, stream>>>(x, xb, N);
    k_wbt<<<(NCOLS * (KP / 8) + 255) / 256, 256, 0, stream>>>(W1, wbt);
    k_wc2<<<4, 256, 0, stream>>>(W2, Wc2);

    // CSR build
    k_count<<<gE, 256, 0, stream>>>(erow, cnt, E);
    k_dis<<<gN, 256, 0, stream>>>(cnt, dis, N);
    k_scan1<<<NB, 256, 0, stream>>>(cnt, off, bsum, N);
    k_scan2<<<1, 256, 0, stream>>>(bsum, NB);
    k_scan3<<<gN, 256, 0, stream>>>(off, cur, bsum, N, E);
    k_scatter<<<gE, 256, 0, stream>>>(erow, ecol, dis, cur, es, E);

    // layer 1: MFMA GEMM
    dim3 g1((N + 127) / 128, 3);
    k_gemm1_mfma<<<g1, 256, 0, stream>>>(xb, wbt, (float2*)u, (float2*)s, wb, N);

    int nw4 = (N + 3) / 4;                    // 4 rows per wave
    int gP4 = (nw4 * 64 + 255) / 256;
    // sb = bf16( s + 2*prop(wb) )
    k_prop_b2b<<<gP4, 256, 0, stream>>>(off, es, wb, (const float2*)s, sb, N);
    // hb(=wb) = bf16 relu( u + prop(sb) + b1 )
    k_prop_b2f_relu<<<gP4, 256, 0, stream>>>(off, es, sb, (const float2*)u, b1, wb, N);

    // layer 2
    k_gemm2<<<(N + 31) / 32, 256, 0, stream>>>(wb, Wc2, b2, out, s2, w2, N);
    k_prop2_csr<<<gN, 256, 0, stream>>>(off, es, w2, s2, s2, 2.0f, N);
    k_prop2_csr<<<gN, 256, 0, stream>>>(off, es, s2, out, out, 1.0f, N);
}